// Round 6
// baseline (432.198 us; speedup 1.0000x reference)
//
#include <hip/hip_runtime.h>
#include <hip/hip_bf16.h>

typedef __bf16 bf16x8 __attribute__((ext_vector_type(8)));
typedef __bf16 bf16x4 __attribute__((ext_vector_type(4)));
typedef float  f32x4  __attribute__((ext_vector_type(4)));

#define BT    2048
#define MDIM  48

// ws byte offsets
#define WS_WVID  0                       // K-major granule layout, 512 KB
#define WS_WV    (512*512*2)
#define WS_WG    (WS_WV + 48*512*2)
#define WS_INTER (WS_WG + 48*512*2)

// ---------------------------------------------------------------- kernel 0
// W_video [512h x 512k] row-major fp32 -> K-major granule bf16:
// granule (kc,h), kc=0..63, at flat16 = kc*512 + h, holds W_video[h][kc*8..kc*8+7].
// W_v / W_g stay row-major bf16.
__global__ __launch_bounds__(256) void convert_weights(
    const float* __restrict__ Wvid, const float* __restrict__ Wv,
    const float* __restrict__ Wg,
    __bf16* __restrict__ wvid_k, __bf16* __restrict__ wv_b,
    __bf16* __restrict__ wg_b) {
    int i = blockIdx.x * blockDim.x + threadIdx.x;
    const int nv = 65536, n2 = 6144;
    if (i < nv) {
        int h = i >> 7, k4 = i & 127;    // 128 float4 per 512-elem row
        float4 f = ((const float4*)Wvid)[i];
        bf16x4 o = {(__bf16)f.x, (__bf16)f.y, (__bf16)f.z, (__bf16)f.w};
        *(bf16x4*)(wvid_k + (size_t)(((k4 >> 1) * 512 + h) * 8 + (k4 & 1) * 4)) = o;
    } else if (i < nv + n2) {
        int j = i - nv;
        float4 f = ((const float4*)Wv)[j];
        bf16x4 o = {(__bf16)f.x, (__bf16)f.y, (__bf16)f.z, (__bf16)f.w};
        ((bf16x4*)wv_b)[j] = o;
    } else {
        int j = i - nv - n2;
        float4 f = ((const float4*)Wg)[j];
        bf16x4 o = {(__bf16)f.x, (__bf16)f.y, (__bf16)f.z, (__bf16)f.w};
        ((bf16x4*)wg_b)[j] = o;
    }
}

// ---------------------------------------------------------------- kernel 1
__global__ __launch_bounds__(512) void audio_batch(
    const float* __restrict__ audio, const float* __restrict__ Wa,
    const float* __restrict__ ba, const __bf16* __restrict__ wg_b,
    float* __restrict__ inter) {
    __shared__ float  ain[16 * 128];
    __shared__ __bf16 as_s[64 * 17 * 8];

    const int bt0 = blockIdx.x * 16;
    const int t   = threadIdx.x;

    ((float4*)ain)[t] = ((const float4*)(audio + (size_t)bt0 * 128))[t];
    __syncthreads();

    float acc[16];
    float bias = ba[t];
    #pragma unroll
    for (int b = 0; b < 16; ++b) acc[b] = bias;
    const float4* wr = (const float4*)(Wa + (size_t)t * 128);
    #pragma unroll 4
    for (int k4 = 0; k4 < 32; ++k4) {
        float4 wv = wr[k4];
        #pragma unroll
        for (int b = 0; b < 16; ++b) {
            float4 av = ((const float4*)ain)[b * 32 + k4];
            acc[b] += av.x*wv.x + av.y*wv.y + av.z*wv.z + av.w*wv.w;
        }
    }
    #pragma unroll
    for (int b = 0; b < 16; ++b)
        as_s[(((t >> 3) * 17 + b) << 3) | (t & 7)] = (__bf16)fmaxf(acc[b], 0.f);
    __syncthreads();

    const int w = t >> 6, lane = t & 63, l16 = lane & 15, quad = lane >> 4;
    if (w < 3) {
        f32x4 c = {0.f, 0.f, 0.f, 0.f};
        const __bf16* bp = wg_b + (size_t)(w * 16 + l16) * 512 + quad * 8;
        const __bf16* ap = &as_s[((quad * 17 + l16)) * 8];
        bf16x8 aC = *(const bf16x8*)ap;
        bf16x8 bC = *(const bf16x8*)bp;
        #pragma unroll
        for (int kt = 0; kt < 16; ++kt) {
            bf16x8 aN, bN;
            if (kt < 15) {
                aN = *(const bf16x8*)(ap + (kt + 1) * (4 * 17 * 8));
                bN = *(const bf16x8*)(bp + (kt + 1) * 32);
            }
            c = __builtin_amdgcn_mfma_f32_16x16x32_bf16(aC, bC, c, 0, 0, 0);
            if (kt < 15) { aC = aN; bC = bN; }
        }
        #pragma unroll
        for (int r = 0; r < 4; ++r)
            inter[(size_t)(bt0 + quad * 4 + r) * 48 + w * 16 + l16] = c[r];
    }
}

// ---------------------------------------------------------------- kernel 2
// FAT-WAVE restructure: 256 threads (4 waves), wave w owns h in [128w,128w+128)
// -> acc[3][8] = 96 VGPRs, which makes the compiler's 64-VGPR tier INFEASIBLE.
// (Rounds 2-5 proved the compiler chooses VGPR=64 whenever the minimal live
// set fits, leaving zero room for any prefetch live-range -> prefetch dist 0
// -> everything at 14%.) 3 blocks/CU (LDS-bound) x 4 waves = 3 waves/SIMD;
// launch_bounds(256,3) -> VGPR cap ~170, room for B-frag pipelining.
// V staged in 4 chunks x 4 kt, 3 granules/thread, serial load+cvt+write at
// chunk end (NO cross-chunk in-flight set: keeps peak pressure ~150, spill
// was the failure mode of rounds 1/3 - watch WRITE_SIZE).
__global__ __launch_bounds__(256, 3) void main_fused(
    const float* __restrict__ video, const float* __restrict__ bvid,
    const __bf16* __restrict__ wvid_k, const __bf16* __restrict__ wv_b,
    const float* __restrict__ Wh, const float* __restrict__ inter_g,
    float* __restrict__ out) {

    __shared__ uint4 pool4[3136];        // 50176 B: V granules, later vact rows
    __shared__ float inter_s[MDIM];
    __shared__ float z_s[MDIM];
    __shared__ float alpha_s[MDIM];
    __shared__ float content8[256];

    char* pool = (char*)pool4;

    const int bt   = blockIdx.x;
    const int tid  = threadIdx.x;        // 0..255
    const int w    = tid >> 6;           // 0..3
    const int lane = tid & 63;
    const int l16  = lane & 15;
    const int quad = lane >> 4;

    const float* Vg = video + (size_t)bt * (48 * 512);
    const char*  bbase = (const char*)wvid_k;

    // ---- phase 0
    if (tid < MDIM) { inter_s[tid] = inter_g[bt * MDIM + tid]; z_s[tid] = 0.f; }
    content8[tid] = 0.f;

    // staging map: thread handles 3 granules/chunk: kcl = tid&15,
    // s in {tid>>4, +16, +32}. 16 lanes share an s-row -> 512B coalesced.
    const int kcl = tid & 15;
    const int s_b = tid >> 4;            // 0..15

    // ---- prologue: stage chunk 0 (kc 0..15, all 48 s)
    #pragma unroll
    for (int m = 0; m < 3; ++m) {
        const int s = s_b + m * 16;
        const float4* p = (const float4*)(Vg + s * 512 + kcl * 8);
        float4 x = p[0], y = p[1];
        bf16x8 g = {(__bf16)x.x, (__bf16)x.y, (__bf16)x.z, (__bf16)x.w,
                    (__bf16)y.x, (__bf16)y.y, (__bf16)y.z, (__bf16)y.w};
        *(bf16x8*)(pool + (kcl * 49 + s) * 16) = g;
    }

    // B byte addr for (kt,j): kt*32768 + quad*8192 + (w*128 + j*16 + l16)*16
    const int bIdx0 = quad * 8192 + (w * 128 + l16) * 16;

    f32x4 acc[3][8];
    #pragma unroll
    for (int mt = 0; mt < 3; ++mt)
        #pragma unroll
        for (int j = 0; j < 8; ++j) {
            f32x4 z = {0.f, 0.f, 0.f, 0.f};
            acc[mt][j] = z;
        }

    __syncthreads();

    // ---- phase 1+2: 4 chunks x 4 kt; stage chunk c+1 at end of chunk c
    #pragma unroll
    for (int c = 0; c < 4; ++c) {
        #pragma unroll
        for (int k = 0; k < 4; ++k) {
            const int kt = c * 4 + k;
            bf16x8 a[3];
            #pragma unroll
            for (int mt = 0; mt < 3; ++mt)
                a[mt] = *(const bf16x8*)(pool + ((4 * kt + quad) * 49 + mt * 16 + l16) * 16);
            bf16x8 b[8];
            #pragma unroll
            for (int j = 0; j < 8; ++j)
                b[j] = *(const bf16x8*)(bbase + bIdx0 + kt * 32768 + j * 256);
            #pragma unroll
            for (int mt = 0; mt < 3; ++mt)
                #pragma unroll
                for (int j = 0; j < 8; ++j)
                    acc[mt][j] = __builtin_amdgcn_mfma_f32_16x16x32_bf16(
                                     a[mt], b[j], acc[mt][j], 0, 0, 0);
        }
        if (c < 3) {
            #pragma unroll
            for (int m = 0; m < 3; ++m) {
                const int s  = s_b + m * 16;
                const int kc = (c + 1) * 16 + kcl;
                const float4* p = (const float4*)(Vg + s * 512 + kc * 8);
                float4 x = p[0], y = p[1];
                bf16x8 g = {(__bf16)x.x, (__bf16)x.y, (__bf16)x.z, (__bf16)x.w,
                            (__bf16)y.x, (__bf16)y.y, (__bf16)y.z, (__bf16)y.w};
                *(bf16x8*)(pool + (kc * 49 + s) * 16) = g;
            }
        }
        __syncthreads();   // chunk c+1 visible; final one fences pool reuse
    }

    // epilogue: relu+bias -> vact rows of 1040 B. D: row(s)=quad*4+r, col(h)=l16
    #pragma unroll
    for (int j = 0; j < 8; ++j) {
        const int h = w * 128 + j * 16 + l16;
        float bias = bvid[h];            // L2-hot scalar load
        #pragma unroll
        for (int mt = 0; mt < 3; ++mt) {
            #pragma unroll
            for (int r = 0; r < 4; ++r) {
                const int s = mt * 16 + quad * 4 + r;
                *(__bf16*)(pool + s * 1040 + h * 2) =
                    (__bf16)fmaxf(acc[mt][j][r] + bias, 0.f);
            }
        }
    }
    __syncthreads();

    // ---- phase 3: content = vact @ Wv^T + inter; z[s] += tanh(.)*Wh[m]
    // 4 waves: wave w does full tiles T=w and T=w+4 (T=ti*3+tj, 0..7),
    // plus tile 8 (ti=tj=2) split: wave w does kt = 4w..4w+3.
    {
        #pragma unroll
        for (int half = 0; half < 2; ++half) {
            const int T  = w + half * 4;
            const int ti = T / 3, tj = T - ti * 3;
            const __bf16* bp = wv_b + (size_t)(tj * 16 + l16) * 512 + quad * 8;
            const char*   ap = pool + (ti * 16 + l16) * 1040 + quad * 16;
            f32x4 c3e = {0.f, 0.f, 0.f, 0.f};
            f32x4 c3o = {0.f, 0.f, 0.f, 0.f};
            #pragma unroll
            for (int kt = 0; kt < 16; kt += 2) {
                bf16x8 a0 = *(const bf16x8*)(ap + kt * 64);
                bf16x8 b0 = *(const bf16x8*)(bp + kt * 32);
                c3e = __builtin_amdgcn_mfma_f32_16x16x32_bf16(a0, b0, c3e, 0, 0, 0);
                bf16x8 a1 = *(const bf16x8*)(ap + (kt + 1) * 64);
                bf16x8 b1 = *(const bf16x8*)(bp + (kt + 1) * 32);
                c3o = __builtin_amdgcn_mfma_f32_16x16x32_bf16(a1, b1, c3o, 0, 0, 0);
            }
            f32x4 c3 = c3e + c3o;
            float wh = Wh[tj * 16 + l16];
            #pragma unroll
            for (int r = 0; r < 4; ++r) {
                const int s = ti * 16 + quad * 4 + r;
                float contrib = tanhf(c3[r] + inter_s[s]) * wh;
                contrib += __shfl_xor(contrib, 1);
                contrib += __shfl_xor(contrib, 2);
                contrib += __shfl_xor(contrib, 4);
                contrib += __shfl_xor(contrib, 8);
                if (l16 == 0) atomicAdd(&z_s[s], contrib);
            }
        }
        f32x4 p8 = {0.f, 0.f, 0.f, 0.f};
        #pragma unroll
        for (int q = 0; q < 4; ++q) {
            const int kt = 4 * w + q;
            bf16x8 a8 = *(const bf16x8*)(pool + (32 + l16) * 1040 + kt * 64 + quad * 16);
            bf16x8 b8 = *(const bf16x8*)(wv_b + (size_t)(32 + l16) * 512 + kt * 32 + quad * 8);
            p8 = __builtin_amdgcn_mfma_f32_16x16x32_bf16(a8, b8, p8, 0, 0, 0);
        }
        #pragma unroll
        for (int r = 0; r < 4; ++r)
            atomicAdd(&content8[(quad * 4 + r) * 16 + l16], p8[r]);
    }
    __syncthreads();

    if (w == 0) {
        float wh = Wh[32 + l16];
        #pragma unroll
        for (int r = 0; r < 4; ++r) {
            const int s = 32 + quad * 4 + r;
            float contrib = tanhf(content8[(quad * 4 + r) * 16 + l16] + inter_s[s]) * wh;
            contrib += __shfl_xor(contrib, 1);
            contrib += __shfl_xor(contrib, 2);
            contrib += __shfl_xor(contrib, 4);
            contrib += __shfl_xor(contrib, 8);
            if (l16 == 0) atomicAdd(&z_s[s], contrib);
        }
    }
    __syncthreads();

    // ---- phase 4: softmax over z[48] (wave 0)
    if (w == 0) {
        float x = (lane < MDIM) ? z_s[lane] : -INFINITY;
        float mx = x;
        #pragma unroll
        for (int off = 32; off >= 1; off >>= 1) mx = fmaxf(mx, __shfl_xor(mx, off));
        float e = (lane < MDIM) ? expf(x - mx) : 0.f;
        float sm = e;
        #pragma unroll
        for (int off = 32; off >= 1; off >>= 1) sm += __shfl_xor(sm, off);
        if (lane < MDIM) alpha_s[lane] = e / sm;
    }
    __syncthreads();

    // ---- phase 5: c[h] = sum_s alpha[s] * V[s][h]; 2 h per thread
    float a5 = 0.f, b5 = 0.f;
    #pragma unroll
    for (int s = 0; s < MDIM; ++s) {
        const float al = alpha_s[s];
        a5 += al * Vg[s * 512 + tid];
        b5 += al * Vg[s * 512 + 256 + tid];
    }
    out[(size_t)bt * 512 + tid]       = a5;
    out[(size_t)bt * 512 + 256 + tid] = b5;
}

// ---------------------------------------------------------------- launch
extern "C" void kernel_launch(void* const* d_in, const int* in_sizes, int n_in,
                              void* d_out, int out_size, void* d_ws, size_t ws_size,
                              hipStream_t stream) {
    const float* audio   = (const float*)d_in[0];
    const float* video   = (const float*)d_in[1];
    const float* W_audio = (const float*)d_in[2];
    const float* b_audio = (const float*)d_in[3];
    const float* W_video = (const float*)d_in[4];
    const float* b_video = (const float*)d_in[5];
    const float* W_v     = (const float*)d_in[6];
    const float* W_g     = (const float*)d_in[7];
    const float* W_h     = (const float*)d_in[8];
    float* out = (float*)d_out;

    char* ws = (char*)d_ws;
    __bf16* wvid_k = (__bf16*)(ws + WS_WVID);
    __bf16* wv_b   = (__bf16*)(ws + WS_WV);
    __bf16* wg_b   = (__bf16*)(ws + WS_WG);
    float*  inter  = (float*)(ws + WS_INTER);

    convert_weights<<<304, 256, 0, stream>>>(W_video, W_v, W_g, wvid_k, wv_b, wg_b);
    audio_batch<<<BT / 16, 512, 0, stream>>>(audio, W_audio, b_audio, wg_b, inter);
    main_fused<<<BT, 256, 0, stream>>>(video, b_video, wvid_k, wv_b, W_h, inter, out);
}

// Round 7
// 400.469 us; speedup vs baseline: 1.0792x; 1.0792x over previous
//
#include <hip/hip_runtime.h>
#include <hip/hip_bf16.h>

typedef __bf16 bf16x8 __attribute__((ext_vector_type(8)));
typedef __bf16 bf16x4 __attribute__((ext_vector_type(4)));
typedef float  f32x4  __attribute__((ext_vector_type(4)));

#define BT    2048
#define MDIM  48

// ws byte offsets
#define WS_WVID  0                       // K-major granule layout, 512 KB
#define WS_WV    (512*512*2)
#define WS_WG    (WS_WV + 48*512*2)
#define WS_INTER (WS_WG + 48*512*2)

// ---------------------------------------------------------------- kernel 0
// W_video [512h x 512k] row-major fp32 -> K-major granule bf16:
// granule (kc,h), kc=0..63, at flat16 = kc*512 + h, holds W_video[h][kc*8..kc*8+7].
// W_v / W_g stay row-major bf16.
__global__ __launch_bounds__(256) void convert_weights(
    const float* __restrict__ Wvid, const float* __restrict__ Wv,
    const float* __restrict__ Wg,
    __bf16* __restrict__ wvid_k, __bf16* __restrict__ wv_b,
    __bf16* __restrict__ wg_b) {
    int i = blockIdx.x * blockDim.x + threadIdx.x;
    const int nv = 65536, n2 = 6144;
    if (i < nv) {
        int h = i >> 7, k4 = i & 127;    // 128 float4 per 512-elem row
        float4 f = ((const float4*)Wvid)[i];
        bf16x4 o = {(__bf16)f.x, (__bf16)f.y, (__bf16)f.z, (__bf16)f.w};
        *(bf16x4*)(wvid_k + (size_t)(((k4 >> 1) * 512 + h) * 8 + (k4 & 1) * 4)) = o;
    } else if (i < nv + n2) {
        int j = i - nv;
        float4 f = ((const float4*)Wv)[j];
        bf16x4 o = {(__bf16)f.x, (__bf16)f.y, (__bf16)f.z, (__bf16)f.w};
        ((bf16x4*)wv_b)[j] = o;
    } else {
        int j = i - nv - n2;
        float4 f = ((const float4*)Wg)[j];
        bf16x4 o = {(__bf16)f.x, (__bf16)f.y, (__bf16)f.z, (__bf16)f.w};
        ((bf16x4*)wg_b)[j] = o;
    }
}

// ---------------------------------------------------------------- kernel 1
__global__ __launch_bounds__(512) void audio_batch(
    const float* __restrict__ audio, const float* __restrict__ Wa,
    const float* __restrict__ ba, const __bf16* __restrict__ wg_b,
    float* __restrict__ inter) {
    __shared__ float  ain[16 * 128];
    __shared__ __bf16 as_s[64 * 17 * 8];

    const int bt0 = blockIdx.x * 16;
    const int t   = threadIdx.x;

    ((float4*)ain)[t] = ((const float4*)(audio + (size_t)bt0 * 128))[t];
    __syncthreads();

    float acc[16];
    float bias = ba[t];
    #pragma unroll
    for (int b = 0; b < 16; ++b) acc[b] = bias;
    const float4* wr = (const float4*)(Wa + (size_t)t * 128);
    #pragma unroll 4
    for (int k4 = 0; k4 < 32; ++k4) {
        float4 wv = wr[k4];
        #pragma unroll
        for (int b = 0; b < 16; ++b) {
            float4 av = ((const float4*)ain)[b * 32 + k4];
            acc[b] += av.x*wv.x + av.y*wv.y + av.z*wv.z + av.w*wv.w;
        }
    }
    #pragma unroll
    for (int b = 0; b < 16; ++b)
        as_s[(((t >> 3) * 17 + b) << 3) | (t & 7)] = (__bf16)fmaxf(acc[b], 0.f);
    __syncthreads();

    const int w = t >> 6, lane = t & 63, l16 = lane & 15, quad = lane >> 4;
    if (w < 3) {
        f32x4 c = {0.f, 0.f, 0.f, 0.f};
        const __bf16* bp = wg_b + (size_t)(w * 16 + l16) * 512 + quad * 8;
        const __bf16* ap = &as_s[((quad * 17 + l16)) * 8];
        bf16x8 aC = *(const bf16x8*)ap;
        bf16x8 bC = *(const bf16x8*)bp;
        #pragma unroll
        for (int kt = 0; kt < 16; ++kt) {
            bf16x8 aN, bN;
            if (kt < 15) {
                aN = *(const bf16x8*)(ap + (kt + 1) * (4 * 17 * 8));
                bN = *(const bf16x8*)(bp + (kt + 1) * 32);
            }
            c = __builtin_amdgcn_mfma_f32_16x16x32_bf16(aC, bC, c, 0, 0, 0);
            if (kt < 15) { aC = aN; bC = bN; }
        }
        #pragma unroll
        for (int r = 0; r < 4; ++r)
            inter[(size_t)(bt0 + quad * 4 + r) * 48 + w * 16 + l16] = c[r];
    }
}

// ---------------------------------------------------------------- kernel 2
// FAT-WAVE (4 waves x 256 thr, wave owns 128 h) + UNCAPPED registers.
// Register-budget decode from rounds 1-6 (observed VGPR counts):
//   effective cap = 256 / launch_bounds_arg2:
//   (512,6)->40, (512,4)->64, (512,3)->64(chose), (256,3)->84 + acc SPILL
//   (acc[3][8]=96 > 84 -> 84 MB scratch WRITE_SIZE, 203us).
// (256,1) -> cap 256: compiler takes what the live set needs (~140-170).
// Occupancy remains LDS-bound at 3 blocks/CU = 3 waves/SIMD (<=170 VGPR ok).
// V staging: loads for chunk c+1 are issued at the TOP of chunk c (before
// the 96-MFMA cluster), cvt+ds_write after it -- issue-early, affordable now
// that staging regs (24) don't compete with a 64-reg cap.
// Watch: WRITE_SIZE must drop 84 MB -> ~4 MB (spill gone).
__global__ __launch_bounds__(256, 1) void main_fused(
    const float* __restrict__ video, const float* __restrict__ bvid,
    const __bf16* __restrict__ wvid_k, const __bf16* __restrict__ wv_b,
    const float* __restrict__ Wh, const float* __restrict__ inter_g,
    float* __restrict__ out) {

    __shared__ uint4 pool4[3136];        // 50176 B: V granules, later vact rows
    __shared__ float inter_s[MDIM];
    __shared__ float z_s[MDIM];
    __shared__ float alpha_s[MDIM];
    __shared__ float content8[256];

    char* pool = (char*)pool4;

    const int bt   = blockIdx.x;
    const int tid  = threadIdx.x;        // 0..255
    const int w    = tid >> 6;           // 0..3
    const int lane = tid & 63;
    const int l16  = lane & 15;
    const int quad = lane >> 4;

    const float* Vg = video + (size_t)bt * (48 * 512);
    const char*  bbase = (const char*)wvid_k;

    // ---- phase 0
    if (tid < MDIM) { inter_s[tid] = inter_g[bt * MDIM + tid]; z_s[tid] = 0.f; }
    content8[tid] = 0.f;

    // staging map: thread handles 3 granules/chunk: kcl = tid&15,
    // s in {tid>>4, +16, +32}. 16 lanes share an s-row -> 512B coalesced.
    const int kcl = tid & 15;
    const int s_b = tid >> 4;            // 0..15

    // ---- prologue: stage chunk 0 (kc 0..15, all 48 s)
    #pragma unroll
    for (int m = 0; m < 3; ++m) {
        const int s = s_b + m * 16;
        const float4* p = (const float4*)(Vg + s * 512 + kcl * 8);
        float4 x = p[0], y = p[1];
        bf16x8 g = {(__bf16)x.x, (__bf16)x.y, (__bf16)x.z, (__bf16)x.w,
                    (__bf16)y.x, (__bf16)y.y, (__bf16)y.z, (__bf16)y.w};
        *(bf16x8*)(pool + (kcl * 49 + s) * 16) = g;
    }

    // B byte addr for (kt,j): kt*32768 + quad*8192 + (w*128 + j*16 + l16)*16
    const int bIdx0 = quad * 8192 + (w * 128 + l16) * 16;

    f32x4 acc[3][8];
    #pragma unroll
    for (int mt = 0; mt < 3; ++mt)
        #pragma unroll
        for (int j = 0; j < 8; ++j) {
            f32x4 z = {0.f, 0.f, 0.f, 0.f};
            acc[mt][j] = z;
        }

    __syncthreads();

    // ---- phase 1+2: 4 chunks x 4 kt; issue-early staging of chunk c+1
    #pragma unroll
    for (int c = 0; c < 4; ++c) {
        // issue chunk-(c+1) loads BEFORE the MFMA cluster (latency hides)
        float4 px[3], py[3];
        if (c < 3) {
            #pragma unroll
            for (int m = 0; m < 3; ++m) {
                const int s  = s_b + m * 16;
                const int kc = (c + 1) * 16 + kcl;
                const float4* p = (const float4*)(Vg + s * 512 + kc * 8);
                px[m] = p[0]; py[m] = p[1];
            }
        }
        #pragma unroll
        for (int k = 0; k < 4; ++k) {
            const int kt = c * 4 + k;
            bf16x8 a[3];
            #pragma unroll
            for (int mt = 0; mt < 3; ++mt)
                a[mt] = *(const bf16x8*)(pool + ((4 * kt + quad) * 49 + mt * 16 + l16) * 16);
            bf16x8 b[8];
            #pragma unroll
            for (int j = 0; j < 8; ++j)
                b[j] = *(const bf16x8*)(bbase + bIdx0 + kt * 32768 + j * 256);
            #pragma unroll
            for (int mt = 0; mt < 3; ++mt)
                #pragma unroll
                for (int j = 0; j < 8; ++j)
                    acc[mt][j] = __builtin_amdgcn_mfma_f32_16x16x32_bf16(
                                     a[mt], b[j], acc[mt][j], 0, 0, 0);
        }
        if (c < 3) {
            #pragma unroll
            for (int m = 0; m < 3; ++m) {
                const int s  = s_b + m * 16;
                const int kc = (c + 1) * 16 + kcl;
                bf16x8 g = {(__bf16)px[m].x, (__bf16)px[m].y, (__bf16)px[m].z, (__bf16)px[m].w,
                            (__bf16)py[m].x, (__bf16)py[m].y, (__bf16)py[m].z, (__bf16)py[m].w};
                *(bf16x8*)(pool + (kc * 49 + s) * 16) = g;
            }
        }
        __syncthreads();   // chunk c+1 visible; final one fences pool reuse
    }

    // epilogue: relu+bias -> vact rows of 1040 B. D: row(s)=quad*4+r, col(h)=l16
    #pragma unroll
    for (int j = 0; j < 8; ++j) {
        const int h = w * 128 + j * 16 + l16;
        float bias = bvid[h];            // L2-hot scalar load
        #pragma unroll
        for (int mt = 0; mt < 3; ++mt) {
            #pragma unroll
            for (int r = 0; r < 4; ++r) {
                const int s = mt * 16 + quad * 4 + r;
                *(__bf16*)(pool + s * 1040 + h * 2) =
                    (__bf16)fmaxf(acc[mt][j][r] + bias, 0.f);
            }
        }
    }
    __syncthreads();

    // ---- phase 3: content = vact @ Wv^T + inter; z[s] += tanh(.)*Wh[m]
    // 4 waves: wave w does full tiles T=w and T=w+4 (T=ti*3+tj, 0..7),
    // plus tile 8 (ti=tj=2) split: wave w does kt = 4w..4w+3.
    {
        #pragma unroll
        for (int half = 0; half < 2; ++half) {
            const int T  = w + half * 4;
            const int ti = T / 3, tj = T - ti * 3;
            const __bf16* bp = wv_b + (size_t)(tj * 16 + l16) * 512 + quad * 8;
            const char*   ap = pool + (ti * 16 + l16) * 1040 + quad * 16;
            f32x4 c3e = {0.f, 0.f, 0.f, 0.f};
            f32x4 c3o = {0.f, 0.f, 0.f, 0.f};
            #pragma unroll
            for (int kt = 0; kt < 16; kt += 2) {
                bf16x8 a0 = *(const bf16x8*)(ap + kt * 64);
                bf16x8 b0 = *(const bf16x8*)(bp + kt * 32);
                c3e = __builtin_amdgcn_mfma_f32_16x16x32_bf16(a0, b0, c3e, 0, 0, 0);
                bf16x8 a1 = *(const bf16x8*)(ap + (kt + 1) * 64);
                bf16x8 b1 = *(const bf16x8*)(bp + (kt + 1) * 32);
                c3o = __builtin_amdgcn_mfma_f32_16x16x32_bf16(a1, b1, c3o, 0, 0, 0);
            }
            f32x4 c3 = c3e + c3o;
            float wh = Wh[tj * 16 + l16];
            #pragma unroll
            for (int r = 0; r < 4; ++r) {
                const int s = ti * 16 + quad * 4 + r;
                float contrib = tanhf(c3[r] + inter_s[s]) * wh;
                contrib += __shfl_xor(contrib, 1);
                contrib += __shfl_xor(contrib, 2);
                contrib += __shfl_xor(contrib, 4);
                contrib += __shfl_xor(contrib, 8);
                if (l16 == 0) atomicAdd(&z_s[s], contrib);
            }
        }
        f32x4 p8 = {0.f, 0.f, 0.f, 0.f};
        #pragma unroll
        for (int q = 0; q < 4; ++q) {
            const int kt = 4 * w + q;
            bf16x8 a8 = *(const bf16x8*)(pool + (32 + l16) * 1040 + kt * 64 + quad * 16);
            bf16x8 b8 = *(const bf16x8*)(wv_b + (size_t)(32 + l16) * 512 + kt * 32 + quad * 8);
            p8 = __builtin_amdgcn_mfma_f32_16x16x32_bf16(a8, b8, p8, 0, 0, 0);
        }
        #pragma unroll
        for (int r = 0; r < 4; ++r)
            atomicAdd(&content8[(quad * 4 + r) * 16 + l16], p8[r]);
    }
    __syncthreads();

    if (w == 0) {
        float wh = Wh[32 + l16];
        #pragma unroll
        for (int r = 0; r < 4; ++r) {
            const int s = 32 + quad * 4 + r;
            float contrib = tanhf(content8[(quad * 4 + r) * 16 + l16] + inter_s[s]) * wh;
            contrib += __shfl_xor(contrib, 1);
            contrib += __shfl_xor(contrib, 2);
            contrib += __shfl_xor(contrib, 4);
            contrib += __shfl_xor(contrib, 8);
            if (l16 == 0) atomicAdd(&z_s[s], contrib);
        }
    }
    __syncthreads();

    // ---- phase 4: softmax over z[48] (wave 0)
    if (w == 0) {
        float x = (lane < MDIM) ? z_s[lane] : -INFINITY;
        float mx = x;
        #pragma unroll
        for (int off = 32; off >= 1; off >>= 1) mx = fmaxf(mx, __shfl_xor(mx, off));
        float e = (lane < MDIM) ? expf(x - mx) : 0.f;
        float sm = e;
        #pragma unroll
        for (int off = 32; off >= 1; off >>= 1) sm += __shfl_xor(sm, off);
        if (lane < MDIM) alpha_s[lane] = e / sm;
    }
    __syncthreads();

    // ---- phase 5: c[h] = sum_s alpha[s] * V[s][h]; 2 h per thread
    float a5 = 0.f, b5 = 0.f;
    #pragma unroll
    for (int s = 0; s < MDIM; ++s) {
        const float al = alpha_s[s];
        a5 += al * Vg[s * 512 + tid];
        b5 += al * Vg[s * 512 + 256 + tid];
    }
    out[(size_t)bt * 512 + tid]       = a5;
    out[(size_t)bt * 512 + 256 + tid] = b5;
}

// ---------------------------------------------------------------- launch
extern "C" void kernel_launch(void* const* d_in, const int* in_sizes, int n_in,
                              void* d_out, int out_size, void* d_ws, size_t ws_size,
                              hipStream_t stream) {
    const float* audio   = (const float*)d_in[0];
    const float* video   = (const float*)d_in[1];
    const float* W_audio = (const float*)d_in[2];
    const float* b_audio = (const float*)d_in[3];
    const float* W_video = (const float*)d_in[4];
    const float* b_video = (const float*)d_in[5];
    const float* W_v     = (const float*)d_in[6];
    const float* W_g     = (const float*)d_in[7];
    const float* W_h     = (const float*)d_in[8];
    float* out = (float*)d_out;

    char* ws = (char*)d_ws;
    __bf16* wvid_k = (__bf16*)(ws + WS_WVID);
    __bf16* wv_b   = (__bf16*)(ws + WS_WV);
    __bf16* wg_b   = (__bf16*)(ws + WS_WG);
    float*  inter  = (float*)(ws + WS_INTER);

    convert_weights<<<304, 256, 0, stream>>>(W_video, W_v, W_g, wvid_k, wv_b, wg_b);
    audio_batch<<<BT / 16, 512, 0, stream>>>(audio, W_audio, b_audio, wg_b, inter);
    main_fused<<<BT, 256, 0, stream>>>(video, b_video, wvid_k, wv_b, W_h, inter, out);
}

// Round 8
// 387.283 us; speedup vs baseline: 1.1160x; 1.0340x over previous
//
#include <hip/hip_runtime.h>
#include <hip/hip_bf16.h>

typedef __bf16 bf16x8 __attribute__((ext_vector_type(8)));
typedef __bf16 bf16x4 __attribute__((ext_vector_type(4)));
typedef float  f32x4  __attribute__((ext_vector_type(4)));

#define BT    2048
#define MDIM  48

// ws byte offsets
#define WS_WVID  0                       // K-major granule layout, 512 KB
#define WS_WV    (512*512*2)
#define WS_WG    (WS_WV + 48*512*2)
#define WS_INTER (WS_WG + 48*512*2)

// ---------------------------------------------------------------- kernel 0
__global__ __launch_bounds__(256) void convert_weights(
    const float* __restrict__ Wvid, const float* __restrict__ Wv,
    const float* __restrict__ Wg,
    __bf16* __restrict__ wvid_k, __bf16* __restrict__ wv_b,
    __bf16* __restrict__ wg_b) {
    int i = blockIdx.x * blockDim.x + threadIdx.x;
    const int nv = 65536, n2 = 6144;
    if (i < nv) {
        int h = i >> 7, k4 = i & 127;    // 128 float4 per 512-elem row
        float4 f = ((const float4*)Wvid)[i];
        bf16x4 o = {(__bf16)f.x, (__bf16)f.y, (__bf16)f.z, (__bf16)f.w};
        *(bf16x4*)(wvid_k + (size_t)(((k4 >> 1) * 512 + h) * 8 + (k4 & 1) * 4)) = o;
    } else if (i < nv + n2) {
        int j = i - nv;
        float4 f = ((const float4*)Wv)[j];
        bf16x4 o = {(__bf16)f.x, (__bf16)f.y, (__bf16)f.z, (__bf16)f.w};
        ((bf16x4*)wv_b)[j] = o;
    } else {
        int j = i - nv - n2;
        float4 f = ((const float4*)Wg)[j];
        bf16x4 o = {(__bf16)f.x, (__bf16)f.y, (__bf16)f.z, (__bf16)f.w};
        ((bf16x4*)wg_b)[j] = o;
    }
}

// ---------------------------------------------------------------- kernel 1
__global__ __launch_bounds__(512) void audio_batch(
    const float* __restrict__ audio, const float* __restrict__ Wa,
    const float* __restrict__ ba, const __bf16* __restrict__ wg_b,
    float* __restrict__ inter) {
    __shared__ float  ain[16 * 128];
    __shared__ __bf16 as_s[64 * 17 * 8];

    const int bt0 = blockIdx.x * 16;
    const int t   = threadIdx.x;

    ((float4*)ain)[t] = ((const float4*)(audio + (size_t)bt0 * 128))[t];
    __syncthreads();

    float acc[16];
    float bias = ba[t];
    #pragma unroll
    for (int b = 0; b < 16; ++b) acc[b] = bias;
    const float4* wr = (const float4*)(Wa + (size_t)t * 128);
    #pragma unroll 4
    for (int k4 = 0; k4 < 32; ++k4) {
        float4 wv = wr[k4];
        #pragma unroll
        for (int b = 0; b < 16; ++b) {
            float4 av = ((const float4*)ain)[b * 32 + k4];
            acc[b] += av.x*wv.x + av.y*wv.y + av.z*wv.z + av.w*wv.w;
        }
    }
    #pragma unroll
    for (int b = 0; b < 16; ++b)
        as_s[(((t >> 3) * 17 + b) << 3) | (t & 7)] = (__bf16)fmaxf(acc[b], 0.f);
    __syncthreads();

    const int w = t >> 6, lane = t & 63, l16 = lane & 15, quad = lane >> 4;
    if (w < 3) {
        f32x4 c = {0.f, 0.f, 0.f, 0.f};
        const __bf16* bp = wg_b + (size_t)(w * 16 + l16) * 512 + quad * 8;
        const __bf16* ap = &as_s[((quad * 17 + l16)) * 8];
        bf16x8 aC = *(const bf16x8*)ap;
        bf16x8 bC = *(const bf16x8*)bp;
        #pragma unroll
        for (int kt = 0; kt < 16; ++kt) {
            bf16x8 aN, bN;
            if (kt < 15) {
                aN = *(const bf16x8*)(ap + (kt + 1) * (4 * 17 * 8));
                bN = *(const bf16x8*)(bp + (kt + 1) * 32);
            }
            c = __builtin_amdgcn_mfma_f32_16x16x32_bf16(aC, bC, c, 0, 0, 0);
            if (kt < 15) { aC = aN; bC = bN; }
        }
        #pragma unroll
        for (int r = 0; r < 4; ++r)
            inter[(size_t)(bt0 + quad * 4 + r) * 48 + w * 16 + l16] = c[r];
    }
}

// ---------------------------------------------------------------- kernel 2
// Fat-wave (4 waves x 256 thr, wave owns 128 h), (256,1) uncapped regs.
// KEY FIX (vmcnt in-order accounting, m135): HBM V-staging loads must NEVER
// be issued before B-fragment loads that are consumed earlier -- any B-wait
// then transitively waits ~900cy for the staging (this poisoned rounds
// 2/4/5/7, all flat at 161-170us; round 6 had the clean order but spilled).
//  - V staging: SERIAL at chunk end (load->cvt->ds_write, consumed at issue
//    point). Exposes ~900cy x 3 chunks ~= 1.5us/block. Queue stays clean.
//  - B: 1-kt register double buffer. bN(kt+1) issued before kt's MFMAs;
//    consuming bC (older) never waits on bN. Covers L2/L3 B latency.
//  - Phase 3: same treatment (both tiles interleaved, 1-deep a/b prefetch);
//    it had the identical load->consume-immediately exposure (~10K cyc).
// Watch: WRITE_SIZE must stay ~4MB (jump = spill = abort).
__global__ __launch_bounds__(256, 1) void main_fused(
    const float* __restrict__ video, const float* __restrict__ bvid,
    const __bf16* __restrict__ wvid_k, const __bf16* __restrict__ wv_b,
    const float* __restrict__ Wh, const float* __restrict__ inter_g,
    float* __restrict__ out) {

    __shared__ uint4 pool4[3136];        // 50176 B: V granules, later vact rows
    __shared__ float inter_s[MDIM];
    __shared__ float z_s[MDIM];
    __shared__ float alpha_s[MDIM];
    __shared__ float content8[256];

    char* pool = (char*)pool4;

    const int bt   = blockIdx.x;
    const int tid  = threadIdx.x;        // 0..255
    const int w    = tid >> 6;           // 0..3
    const int lane = tid & 63;
    const int l16  = lane & 15;
    const int quad = lane >> 4;

    const float* Vg = video + (size_t)bt * (48 * 512);
    const char*  bbase = (const char*)wvid_k;

    // ---- phase 0
    if (tid < MDIM) { inter_s[tid] = inter_g[bt * MDIM + tid]; z_s[tid] = 0.f; }
    content8[tid] = 0.f;

    // staging map: thread handles 3 granules/chunk: kcl = tid&15,
    // s in {tid>>4, +16, +32}. 16 lanes per s-row -> 512B coalesced.
    const int kcl = tid & 15;
    const int s_b = tid >> 4;            // 0..15

    // ---- prologue: stage chunk 0 (kc 0..15, all 48 s), serial
    #pragma unroll
    for (int m = 0; m < 3; ++m) {
        const int s = s_b + m * 16;
        const float4* p = (const float4*)(Vg + s * 512 + kcl * 8);
        float4 x = p[0], y = p[1];
        bf16x8 g = {(__bf16)x.x, (__bf16)x.y, (__bf16)x.z, (__bf16)x.w,
                    (__bf16)y.x, (__bf16)y.y, (__bf16)y.z, (__bf16)y.w};
        *(bf16x8*)(pool + (kcl * 49 + s) * 16) = g;
    }

    // B byte addr for (kt,j): kt*32768 + quad*8192 + (w*128 + j*16 + l16)*16
    const int bIdx0 = quad * 8192 + (w * 128 + l16) * 16;

    // kt=0 B fragments loaded before the barrier (drained by barrier's vmcnt)
    bf16x8 bC[8];
    #pragma unroll
    for (int j = 0; j < 8; ++j)
        bC[j] = *(const bf16x8*)(bbase + bIdx0 + j * 256);

    f32x4 acc[3][8];
    #pragma unroll
    for (int mt = 0; mt < 3; ++mt)
        #pragma unroll
        for (int j = 0; j < 8; ++j) {
            f32x4 z = {0.f, 0.f, 0.f, 0.f};
            acc[mt][j] = z;
        }

    __syncthreads();

    // ---- phase 1+2: 4 chunks x 4 kt; B double-buffered; staging at chunk END
    #pragma unroll
    for (int c = 0; c < 4; ++c) {
        #pragma unroll
        for (int k = 0; k < 4; ++k) {
            const int kt = c * 4 + k;
            bf16x8 a[3];
            #pragma unroll
            for (int mt = 0; mt < 3; ++mt)
                a[mt] = *(const bf16x8*)(pool + ((4 * kt + quad) * 49 + mt * 16 + l16) * 16);
            bf16x8 bN[8];
            if (kt < 15) {
                #pragma unroll
                for (int j = 0; j < 8; ++j)
                    bN[j] = *(const bf16x8*)(bbase + bIdx0 + (kt + 1) * 32768 + j * 256);
            }
            __builtin_amdgcn_sched_barrier(0);   // loads stay above the MFMAs
            #pragma unroll
            for (int mt = 0; mt < 3; ++mt)
                #pragma unroll
                for (int j = 0; j < 8; ++j)
                    acc[mt][j] = __builtin_amdgcn_mfma_f32_16x16x32_bf16(
                                     a[mt], bC[j], acc[mt][j], 0, 0, 0);
            if (kt < 15) {
                #pragma unroll
                for (int j = 0; j < 8; ++j) bC[j] = bN[j];
            }
        }
        if (c < 3) {
            // SERIAL stage of chunk c+1: loads consumed right here (no
            // long-lived HBM loads sitting under later B-waits)
            float4 px[3], py[3];
            #pragma unroll
            for (int m = 0; m < 3; ++m) {
                const int s  = s_b + m * 16;
                const int kc = (c + 1) * 16 + kcl;
                const float4* p = (const float4*)(Vg + s * 512 + kc * 8);
                px[m] = p[0]; py[m] = p[1];
            }
            #pragma unroll
            for (int m = 0; m < 3; ++m) {
                const int s  = s_b + m * 16;
                const int kc = (c + 1) * 16 + kcl;
                bf16x8 g = {(__bf16)px[m].x, (__bf16)px[m].y, (__bf16)px[m].z, (__bf16)px[m].w,
                            (__bf16)py[m].x, (__bf16)py[m].y, (__bf16)py[m].z, (__bf16)py[m].w};
                *(bf16x8*)(pool + (kc * 49 + s) * 16) = g;
            }
        }
        __syncthreads();   // chunk c+1 visible; final one fences pool reuse
    }

    // epilogue: relu+bias -> vact rows of 1040 B. D: row(s)=quad*4+r, col(h)=l16
    #pragma unroll
    for (int j = 0; j < 8; ++j) {
        const int h = w * 128 + j * 16 + l16;
        float bias = bvid[h];            // L2-hot scalar load
        #pragma unroll
        for (int mt = 0; mt < 3; ++mt) {
            #pragma unroll
            for (int r = 0; r < 4; ++r) {
                const int s = mt * 16 + quad * 4 + r;
                *(__bf16*)(pool + s * 1040 + h * 2) =
                    (__bf16)fmaxf(acc[mt][j][r] + bias, 0.f);
            }
        }
    }
    __syncthreads();

    // ---- phase 3: content = vact @ Wv^T + inter; z[s] += tanh(.)*Wh[m]
    // Wave w owns tiles T=w and T=w+4 (T=ti*3+tj), INTERLEAVED with 1-deep
    // a/b prefetch (was load->consume-immediate: ~300-600cy exposed per kt).
    {
        const int TA = w,  TB = w + 4;
        const int tiA = TA / 3, tjA = TA - tiA * 3;
        const int tiB = TB / 3, tjB = TB - tiB * 3;
        const __bf16* bpA = wv_b + (size_t)(tjA * 16 + l16) * 512 + quad * 8;
        const __bf16* bpB = wv_b + (size_t)(tjB * 16 + l16) * 512 + quad * 8;
        const char*   apA = pool + (tiA * 16 + l16) * 1040 + quad * 16;
        const char*   apB = pool + (tiB * 16 + l16) * 1040 + quad * 16;
        f32x4 cA = {0.f, 0.f, 0.f, 0.f};
        f32x4 cB = {0.f, 0.f, 0.f, 0.f};
        bf16x8 aA = *(const bf16x8*)apA;
        bf16x8 aB = *(const bf16x8*)apB;
        bf16x8 bA = *(const bf16x8*)bpA;
        bf16x8 bB = *(const bf16x8*)bpB;
        #pragma unroll
        for (int kt = 0; kt < 16; ++kt) {
            bf16x8 aAn, aBn, bAn, bBn;
            if (kt < 15) {
                aAn = *(const bf16x8*)(apA + (kt + 1) * 64);
                aBn = *(const bf16x8*)(apB + (kt + 1) * 64);
                bAn = *(const bf16x8*)(bpA + (kt + 1) * 32);
                bBn = *(const bf16x8*)(bpB + (kt + 1) * 32);
            }
            __builtin_amdgcn_sched_barrier(0);
            cA = __builtin_amdgcn_mfma_f32_16x16x32_bf16(aA, bA, cA, 0, 0, 0);
            cB = __builtin_amdgcn_mfma_f32_16x16x32_bf16(aB, bB, cB, 0, 0, 0);
            if (kt < 15) { aA = aAn; aB = aBn; bA = bAn; bB = bBn; }
        }
        float whA = Wh[tjA * 16 + l16];
        float whB = Wh[tjB * 16 + l16];
        #pragma unroll
        for (int r = 0; r < 4; ++r) {
            const int sA = tiA * 16 + quad * 4 + r;
            float contrib = tanhf(cA[r] + inter_s[sA]) * whA;
            contrib += __shfl_xor(contrib, 1);
            contrib += __shfl_xor(contrib, 2);
            contrib += __shfl_xor(contrib, 4);
            contrib += __shfl_xor(contrib, 8);
            if (l16 == 0) atomicAdd(&z_s[sA], contrib);
        }
        #pragma unroll
        for (int r = 0; r < 4; ++r) {
            const int sB = tiB * 16 + quad * 4 + r;
            float contrib = tanhf(cB[r] + inter_s[sB]) * whB;
            contrib += __shfl_xor(contrib, 1);
            contrib += __shfl_xor(contrib, 2);
            contrib += __shfl_xor(contrib, 4);
            contrib += __shfl_xor(contrib, 8);
            if (l16 == 0) atomicAdd(&z_s[sB], contrib);
        }
        // tile 8 (ti=tj=2): wave w does kt = 4w..4w+3
        f32x4 p8 = {0.f, 0.f, 0.f, 0.f};
        #pragma unroll
        for (int q = 0; q < 4; ++q) {
            const int kt = 4 * w + q;
            bf16x8 a8 = *(const bf16x8*)(pool + (32 + l16) * 1040 + kt * 64 + quad * 16);
            bf16x8 b8 = *(const bf16x8*)(wv_b + (size_t)(32 + l16) * 512 + kt * 32 + quad * 8);
            p8 = __builtin_amdgcn_mfma_f32_16x16x32_bf16(a8, b8, p8, 0, 0, 0);
        }
        #pragma unroll
        for (int r = 0; r < 4; ++r)
            atomicAdd(&content8[(quad * 4 + r) * 16 + l16], p8[r]);
    }
    __syncthreads();

    if (w == 0) {
        float wh = Wh[32 + l16];
        #pragma unroll
        for (int r = 0; r < 4; ++r) {
            const int s = 32 + quad * 4 + r;
            float contrib = tanhf(content8[(quad * 4 + r) * 16 + l16] + inter_s[s]) * wh;
            contrib += __shfl_xor(contrib, 1);
            contrib += __shfl_xor(contrib, 2);
            contrib += __shfl_xor(contrib, 4);
            contrib += __shfl_xor(contrib, 8);
            if (l16 == 0) atomicAdd(&z_s[s], contrib);
        }
    }
    __syncthreads();

    // ---- phase 4: softmax over z[48] (wave 0)
    if (w == 0) {
        float x = (lane < MDIM) ? z_s[lane] : -INFINITY;
        float mx = x;
        #pragma unroll
        for (int off = 32; off >= 1; off >>= 1) mx = fmaxf(mx, __shfl_xor(mx, off));
        float e = (lane < MDIM) ? expf(x - mx) : 0.f;
        float sm = e;
        #pragma unroll
        for (int off = 32; off >= 1; off >>= 1) sm += __shfl_xor(sm, off);
        if (lane < MDIM) alpha_s[lane] = e / sm;
    }
    __syncthreads();

    // ---- phase 5: c[h] = sum_s alpha[s] * V[s][h]; 2 h per thread
    float a5 = 0.f, b5 = 0.f;
    #pragma unroll
    for (int s = 0; s < MDIM; ++s) {
        const float al = alpha_s[s];
        a5 += al * Vg[s * 512 + tid];
        b5 += al * Vg[s * 512 + 256 + tid];
    }
    out[(size_t)bt * 512 + tid]       = a5;
    out[(size_t)bt * 512 + 256 + tid] = b5;
}

// ---------------------------------------------------------------- launch
extern "C" void kernel_launch(void* const* d_in, const int* in_sizes, int n_in,
                              void* d_out, int out_size, void* d_ws, size_t ws_size,
                              hipStream_t stream) {
    const float* audio   = (const float*)d_in[0];
    const float* video   = (const float*)d_in[1];
    const float* W_audio = (const float*)d_in[2];
    const float* b_audio = (const float*)d_in[3];
    const float* W_video = (const float*)d_in[4];
    const float* b_video = (const float*)d_in[5];
    const float* W_v     = (const float*)d_in[6];
    const float* W_g     = (const float*)d_in[7];
    const float* W_h     = (const float*)d_in[8];
    float* out = (float*)d_out;

    char* ws = (char*)d_ws;
    __bf16* wvid_k = (__bf16*)(ws + WS_WVID);
    __bf16* wv_b   = (__bf16*)(ws + WS_WV);
    __bf16* wg_b   = (__bf16*)(ws + WS_WG);
    float*  inter  = (float*)(ws + WS_INTER);

    convert_weights<<<304, 256, 0, stream>>>(W_video, W_v, W_g, wvid_k, wv_b, wg_b);
    audio_batch<<<BT / 16, 512, 0, stream>>>(audio, W_audio, b_audio, wg_b, inter);
    main_fused<<<BT, 256, 0, stream>>>(video, b_video, wvid_k, wv_b, W_h, inter, out);
}